// Round 2
// baseline (770.649 us; speedup 1.0000x reference)
//
#include <hip/hip_runtime.h>

#define NLEV 20
#define TSIZE (1u << 19)
#define TMASK (TSIZE - 1u)
#define PRIME_Y 2654435761u
#define PRIME_Z 805459861u

typedef float f32x2 __attribute__((ext_vector_type(2)));
typedef float f32x4 __attribute__((ext_vector_type(4)));

// int(16 * 1.39**i) for i in 0..19 — verified, none near an integer boundary.
__device__ __constant__ int kRes[NLEV] = {
    16, 22, 30, 42, 59, 83, 115, 160, 222, 309,
    430, 598, 832, 1156, 1608, 2235, 3107, 4318, 6003, 8344};

__device__ __forceinline__ void make_idx(int l, float px, float py, float pz,
                                         unsigned idx[8], float& wx, float& wy,
                                         float& wz) {
  const float r = (float)kRes[l];
  const float xs0 = px * r, xs1 = py * r, xs2 = pz * r;
  const float f0 = floorf(xs0), f1 = floorf(xs1), f2 = floorf(xs2);
  wx = xs0 - f0;
  wy = xs1 - f1;
  wz = xs2 - f2;
  const unsigned v0 = (unsigned)(int)f0;
  const unsigned v1 = (unsigned)(int)f1;
  const unsigned v2 = (unsigned)(int)f2;
  const unsigned hx0 = v0, hx1 = v0 + 1u;
  const unsigned hy0 = v1 * PRIME_Y, hy1 = (v1 + 1u) * PRIME_Y;
  const unsigned hz0 = v2 * PRIME_Z, hz1 = (v2 + 1u) * PRIME_Z;
  idx[0] = (hx0 ^ hy0 ^ hz0) & TMASK;
  idx[1] = (hx0 ^ hy0 ^ hz1) & TMASK;
  idx[2] = (hx0 ^ hy1 ^ hz0) & TMASK;
  idx[3] = (hx0 ^ hy1 ^ hz1) & TMASK;
  idx[4] = (hx1 ^ hy0 ^ hz0) & TMASK;
  idx[5] = (hx1 ^ hy0 ^ hz1) & TMASK;
  idx[6] = (hx1 ^ hy1 ^ hz0) & TMASK;
  idx[7] = (hx1 ^ hy1 ^ hz1) & TMASK;
}

__device__ __forceinline__ float2 trilerp(const float2 e[8], float wx, float wy,
                                          float wz) {
  const float owx = 1.0f - wx, owy = 1.0f - wy, owz = 1.0f - wz;
  const float c00a = e[0].x * owx + e[4].x * wx;
  const float c01a = e[1].x * owx + e[5].x * wx;
  const float c10a = e[2].x * owx + e[6].x * wx;
  const float c11a = e[3].x * owx + e[7].x * wx;
  const float c0a = c00a * owy + c10a * wy;
  const float c1a = c01a * owy + c11a * wy;
  const float c00b = e[0].y * owx + e[4].y * wx;
  const float c01b = e[1].y * owx + e[5].y * wx;
  const float c10b = e[2].y * owx + e[6].y * wx;
  const float c11b = e[3].y * owx + e[7].y * wx;
  const float c0b = c00b * owy + c10b * wy;
  const float c1b = c01b * owy + c11b * wy;
  return make_float2(c0a * owz + c1a * wz, c0b * owz + c1b * wz);
}

__device__ __forceinline__ float2 encode_one(const float* __restrict__ tables,
                                             int l, float px, float py, float pz) {
  unsigned ia[8];
  float wx, wy, wz;
  make_idx(l, px, py, pz, ia, wx, wy, wz);
  const float2* __restrict__ tbl = (const float2*)tables + (size_t)l * TSIZE;
  float2 e[8];
#pragma unroll
  for (int i = 0; i < 8; ++i) e[i] = tbl[ia[i]];
  return trilerp(e, wx, wy, wz);
}

// Kernel 1: TWO points per thread per level (16 independent gathers issued
// before any dependent lerp — doubles per-wave MLP vs the 8-gather version).
// Level-major dispatch (blockIdx.y = level) keeps ~one 4 MB table per XCD L2.
// Streaming accesses (x reads, ws writes) stay nontemporal so they don't
// evict the table from L2.
__global__ __launch_bounds__(256) void enc_level_kernel(
    const float* __restrict__ x, const float* __restrict__ tables,
    float2* __restrict__ ws, int n) {
  const int l = blockIdx.y;
  const int p0 = blockIdx.x * 512 + threadIdx.x;
  const int p1 = p0 + 256;
  const float2* __restrict__ tbl = (const float2*)tables + (size_t)l * TSIZE;

  if (p1 < n) {
    const float ax = __builtin_nontemporal_load(x + 3 * p0 + 0);
    const float ay = __builtin_nontemporal_load(x + 3 * p0 + 1);
    const float az = __builtin_nontemporal_load(x + 3 * p0 + 2);
    const float bx = __builtin_nontemporal_load(x + 3 * p1 + 0);
    const float by = __builtin_nontemporal_load(x + 3 * p1 + 1);
    const float bz = __builtin_nontemporal_load(x + 3 * p1 + 2);

    unsigned ia[8], ib[8];
    float wxa, wya, wza, wxb, wyb, wzb;
    make_idx(l, ax, ay, az, ia, wxa, wya, wza);
    make_idx(l, bx, by, bz, ib, wxb, wyb, wzb);

    float2 ea[8], eb[8];
#pragma unroll
    for (int i = 0; i < 8; ++i) ea[i] = tbl[ia[i]];
#pragma unroll
    for (int i = 0; i < 8; ++i) eb[i] = tbl[ib[i]];

    const float2 oa = trilerp(ea, wxa, wya, wza);
    const float2 ob = trilerp(eb, wxb, wyb, wzb);
    f32x2 va;
    va.x = oa.x;
    va.y = oa.y;
    f32x2 vb;
    vb.x = ob.x;
    vb.y = ob.y;
    __builtin_nontemporal_store(va, (f32x2*)(ws + (size_t)l * n + p0));
    __builtin_nontemporal_store(vb, (f32x2*)(ws + (size_t)l * n + p1));
  } else if (p0 < n) {
    const float ax = __builtin_nontemporal_load(x + 3 * p0 + 0);
    const float ay = __builtin_nontemporal_load(x + 3 * p0 + 1);
    const float az = __builtin_nontemporal_load(x + 3 * p0 + 2);
    const float2 oa = encode_one(tables, l, ax, ay, az);
    f32x2 va;
    va.x = oa.x;
    va.y = oa.y;
    __builtin_nontemporal_store(va, (f32x2*)(ws + (size_t)l * n + p0));
  }
}

// Kernel 2: transpose ws (20, N, 2) -> out (N, 40) via LDS tile of 256 points.
// LDS row stride 41 floats (odd) to avoid bank conflicts on both phases.
// ws loads are NORMAL (allow L3 hits on freshly-written ws); out stores NT.
__global__ __launch_bounds__(256) void transpose_kernel(
    const float2* __restrict__ ws, float* __restrict__ out, int n) {
  __shared__ float lds[256 * 41];
  const int p0 = blockIdx.x * 256;
  const int t = threadIdx.x;
  const int npts = min(256, n - p0);

#pragma unroll
  for (int l = 0; l < NLEV; ++l) {
    if (t < npts) {
      const float2 v = ws[(size_t)l * n + p0 + t];
      lds[t * 41 + 2 * l + 0] = v.x;
      lds[t * 41 + 2 * l + 1] = v.y;
    }
  }
  __syncthreads();

  const int total4 = npts * 10;  // float4s this block must write
  f32x4* __restrict__ dst = (f32x4*)(out + (size_t)p0 * (NLEV * 2));
#pragma unroll
  for (int k = 0; k < 10; ++k) {
    const int g = t + k * 256;
    if (g < total4) {
      const int pl = g / 10;         // local point
      const int comp = g - pl * 10;  // float4 index within row
      const float* s = &lds[pl * 41 + comp * 4];
      f32x4 v;
      v.x = s[0];
      v.y = s[1];
      v.z = s[2];
      v.w = s[3];
      __builtin_nontemporal_store(v, dst + g);
    }
  }
}

// Fallback: direct per-point, all levels, used only if ws too small.
__global__ __launch_bounds__(256) void hash_enc_kernel(
    const float* __restrict__ x, const float* __restrict__ tables,
    float* __restrict__ out, int n) {
  int p = blockIdx.x * 256 + threadIdx.x;
  if (p >= n) return;
  const float px = x[3 * p + 0];
  const float py = x[3 * p + 1];
  const float pz = x[3 * p + 2];
  float o[NLEV * 2];
#pragma unroll
  for (int l = 0; l < NLEV; ++l) {
    const float2 v = encode_one(tables, l, px, py, pz);
    o[2 * l + 0] = v.x;
    o[2 * l + 1] = v.y;
  }
  float4* __restrict__ dst = (float4*)(out + (size_t)p * (NLEV * 2));
#pragma unroll
  for (int k = 0; k < 10; ++k) {
    dst[k] = make_float4(o[4 * k + 0], o[4 * k + 1], o[4 * k + 2], o[4 * k + 3]);
  }
}

extern "C" void kernel_launch(void* const* d_in, const int* in_sizes, int n_in,
                              void* d_out, int out_size, void* d_ws, size_t ws_size,
                              hipStream_t stream) {
  const float* x = (const float*)d_in[0];       // (N, 3) f32
  const float* tables = (const float*)d_in[1];  // (20, 2^19, 2) f32
  float* out = (float*)d_out;                   // (N, 40) f32
  const int n = in_sizes[0] / 3;
  const size_t ws_needed = (size_t)NLEV * n * 2 * sizeof(float);

  if (ws_size >= ws_needed) {
    const int pblocks2 = (n + 511) / 512;
    dim3 grid1(pblocks2, NLEV);
    enc_level_kernel<<<grid1, 256, 0, stream>>>(x, tables, (float2*)d_ws, n);
    const int pblocks = (n + 255) / 256;
    transpose_kernel<<<pblocks, 256, 0, stream>>>((const float2*)d_ws, out, n);
  } else {
    const int grid = (n + 255) / 256;
    hash_enc_kernel<<<grid, 256, 0, stream>>>(x, tables, out, n);
  }
}

// Round 3
// 685.743 us; speedup vs baseline: 1.1238x; 1.1238x over previous
//
#include <hip/hip_runtime.h>

#define NLEV 20
#define TSIZE (1u << 19)
#define TMASK (TSIZE - 1u)
#define PRIME_Y 2654435761u
#define PRIME_Z 805459861u

typedef float f32x2 __attribute__((ext_vector_type(2)));
typedef float f32x4 __attribute__((ext_vector_type(4)));

// int(16 * 1.39**i) for i in 0..19 — verified, none near an integer boundary.
__device__ __constant__ int kRes[NLEV] = {
    16, 22, 30, 42, 59, 83, 115, 160, 222, 309,
    430, 598, 832, 1156, 1608, 2235, 3107, 4318, 6003, 8344};

// Encode one (point, level). Exploits hash x-adjacency: corners (v0, v0+1)
// with identical y,z have indices (v0^H) and ((v0+1)^H). When v0 is even,
// (v0+1)^H == (v0^H)^1 — the two entries form one aligned 16-B pair, so one
// dwordx4 load fetches both corners. Halves request count for even-v0 lanes
// (50% of lanes): expected -25% L2 gather requests / line traffic overall.
__device__ __forceinline__ float2 encode_one(const float2* __restrict__ tbl,
                                             float r, float px, float py,
                                             float pz) {
  const float xs0 = px * r, xs1 = py * r, xs2 = pz * r;
  const float f0 = floorf(xs0), f1 = floorf(xs1), f2 = floorf(xs2);
  const float wx = xs0 - f0, wy = xs1 - f1, wz = xs2 - f2;
  const unsigned v0 = (unsigned)(int)f0;
  const unsigned v1 = (unsigned)(int)f1;
  const unsigned v2 = (unsigned)(int)f2;

  const unsigned hy0 = v1 * PRIME_Y, hy1 = (v1 + 1u) * PRIME_Y;
  const unsigned hz0 = v2 * PRIME_Z, hz1 = (v2 + 1u) * PRIME_Z;
  unsigned H[4];
  H[0] = hy0 ^ hz0;  // (y0,z0)
  H[1] = hy0 ^ hz1;  // (y0,z1)
  H[2] = hy1 ^ hz0;  // (y1,z0)
  H[3] = hy1 ^ hz1;  // (y1,z1)

  float2 e0[4], e1[4];  // e0[j]: corner x=v0, yz combo j; e1[j]: x=v0+1

  if ((v0 & 1u) == 0u) {
    // even v0: 4x 16-B paired loads
#pragma unroll
    for (int j = 0; j < 4; ++j) {
      const unsigned i0 = (v0 ^ H[j]) & TMASK;
      const f32x4 q = *(const f32x4*)((const float*)tbl + 2u * (i0 & ~1u));
      const bool lo = (i0 & 1u) == 0u;
      e0[j] = lo ? make_float2(q.x, q.y) : make_float2(q.z, q.w);
      e1[j] = lo ? make_float2(q.z, q.w) : make_float2(q.x, q.y);
    }
  } else {
    // odd v0: 8x 8-B loads
#pragma unroll
    for (int j = 0; j < 4; ++j) {
      e0[j] = tbl[(v0 ^ H[j]) & TMASK];
      e1[j] = tbl[((v0 + 1u) ^ H[j]) & TMASK];
    }
  }

  const float owx = 1.0f - wx, owy = 1.0f - wy, owz = 1.0f - wz;

  const float c00a = e0[0].x * owx + e1[0].x * wx;
  const float c01a = e0[1].x * owx + e1[1].x * wx;
  const float c10a = e0[2].x * owx + e1[2].x * wx;
  const float c11a = e0[3].x * owx + e1[3].x * wx;
  const float c0a = c00a * owy + c10a * wy;
  const float c1a = c01a * owy + c11a * wy;

  const float c00b = e0[0].y * owx + e1[0].y * wx;
  const float c01b = e0[1].y * owx + e1[1].y * wx;
  const float c10b = e0[2].y * owx + e1[2].y * wx;
  const float c11b = e0[3].y * owx + e1[3].y * wx;
  const float c0b = c00b * owy + c10b * wy;
  const float c1b = c01b * owy + c11b * wy;

  return make_float2(c0a * owz + c1a * wz, c0b * owz + c1b * wz);
}

// Kernel 1: one (point, level) per thread, level-major dispatch (blockIdx.y =
// level) so each XCD's 4 MB L2 holds ~one level's 4 MB table at a time.
// Streaming accesses (x reads, ws writes) are nontemporal so they don't evict
// the table from L2.
__global__ __launch_bounds__(256) void enc_level_kernel(
    const float* __restrict__ x, const float* __restrict__ tables,
    float2* __restrict__ ws, int n) {
  const int l = blockIdx.y;
  const int p = blockIdx.x * 256 + threadIdx.x;
  if (p >= n) return;
  const float px = __builtin_nontemporal_load(x + 3 * p + 0);
  const float py = __builtin_nontemporal_load(x + 3 * p + 1);
  const float pz = __builtin_nontemporal_load(x + 3 * p + 2);
  const float2* __restrict__ tbl = (const float2*)tables + (size_t)l * TSIZE;
  const float2 v = encode_one(tbl, (float)kRes[l], px, py, pz);
  f32x2 vv;
  vv.x = v.x;
  vv.y = v.y;
  __builtin_nontemporal_store(vv, (f32x2*)(ws + (size_t)l * n + p));
}

// Kernel 2: transpose ws (20, N, 2) -> out (N, 40) via LDS tile of 256 points.
// LDS row stride 41 floats (odd) to avoid bank conflicts on both phases.
// ws loads NT (one-shot stream, don't pollute caches — R1-verified better).
// out stores NORMAL write-back: lets L2 merge the 16-B pieces into full 64-B
// lines before HBM writeback (NT 16-B stores appear not to combine).
__global__ __launch_bounds__(256) void transpose_kernel(
    const float2* __restrict__ ws, float* __restrict__ out, int n) {
  __shared__ float lds[256 * 41];
  const int p0 = blockIdx.x * 256;
  const int t = threadIdx.x;
  const int npts = min(256, n - p0);

#pragma unroll
  for (int l = 0; l < NLEV; ++l) {
    if (t < npts) {
      const f32x2 v =
          __builtin_nontemporal_load((const f32x2*)(ws + (size_t)l * n + p0 + t));
      lds[t * 41 + 2 * l + 0] = v.x;
      lds[t * 41 + 2 * l + 1] = v.y;
    }
  }
  __syncthreads();

  const int total4 = npts * 10;  // float4s this block must write
  f32x4* __restrict__ dst = (f32x4*)(out + (size_t)p0 * (NLEV * 2));
#pragma unroll
  for (int k = 0; k < 10; ++k) {
    const int g = t + k * 256;
    if (g < total4) {
      const int pl = g / 10;         // local point
      const int comp = g - pl * 10;  // float4 index within row
      const float* s = &lds[pl * 41 + comp * 4];
      f32x4 v;
      v.x = s[0];
      v.y = s[1];
      v.z = s[2];
      v.w = s[3];
      dst[g] = v;  // normal store — L2 write-combining
    }
  }
}

// Fallback: direct per-point, all levels, used only if ws too small.
__global__ __launch_bounds__(256) void hash_enc_kernel(
    const float* __restrict__ x, const float* __restrict__ tables,
    float* __restrict__ out, int n) {
  int p = blockIdx.x * 256 + threadIdx.x;
  if (p >= n) return;
  const float px = x[3 * p + 0];
  const float py = x[3 * p + 1];
  const float pz = x[3 * p + 2];
  float o[NLEV * 2];
#pragma unroll
  for (int l = 0; l < NLEV; ++l) {
    const float2* tbl = (const float2*)tables + (size_t)l * TSIZE;
    const float2 v = encode_one(tbl, (float)kRes[l], px, py, pz);
    o[2 * l + 0] = v.x;
    o[2 * l + 1] = v.y;
  }
  float4* __restrict__ dst = (float4*)(out + (size_t)p * (NLEV * 2));
#pragma unroll
  for (int k = 0; k < 10; ++k) {
    dst[k] = make_float4(o[4 * k + 0], o[4 * k + 1], o[4 * k + 2], o[4 * k + 3]);
  }
}

extern "C" void kernel_launch(void* const* d_in, const int* in_sizes, int n_in,
                              void* d_out, int out_size, void* d_ws, size_t ws_size,
                              hipStream_t stream) {
  const float* x = (const float*)d_in[0];       // (N, 3) f32
  const float* tables = (const float*)d_in[1];  // (20, 2^19, 2) f32
  float* out = (float*)d_out;                   // (N, 40) f32
  const int n = in_sizes[0] / 3;
  const size_t ws_needed = (size_t)NLEV * n * 2 * sizeof(float);

  if (ws_size >= ws_needed) {
    const int pblocks = (n + 255) / 256;
    dim3 grid1(pblocks, NLEV);
    enc_level_kernel<<<grid1, 256, 0, stream>>>(x, tables, (float2*)d_ws, n);
    transpose_kernel<<<pblocks, 256, 0, stream>>>((const float2*)d_ws, out, n);
  } else {
    const int grid = (n + 255) / 256;
    hash_enc_kernel<<<grid, 256, 0, stream>>>(x, tables, out, n);
  }
}